// Round 1
// baseline (281.368 us; speedup 1.0000x reference)
//
#include <hip/hip_runtime.h>

// ROIAlign (tf.image.crop_and_resize, bilinear, extrapolation_value=0)
// features: [B=4, H=256, W=256, C=64] f32
// rois:     [B=4, N=64, 4] f32  (x1,y1,x2,y2) in image coords (/1024 to normalize)
// out:      [B=4, N=64, 56, 56, C=64] f32
//
// Layout: 16 threads per spatial output position (b,n,i,j); each thread
// handles 4 consecutive channels via float4. Consecutive lanes -> consecutive
// channels -> fully coalesced loads (4 neighbors) and stores.

#define CROP 56
#define FH 256
#define FW 256
#define FC 64

__global__ __launch_bounds__(256) void roialign_kernel(
    const float* __restrict__ feats,
    const float* __restrict__ rois,
    float* __restrict__ out,
    int total_threads)
{
    int g = blockIdx.x * blockDim.x + threadIdx.x;
    if (g >= total_threads) return;

    int pos = g >> 4;            // spatial position index: b*64*56*56 + n*56*56 + i*56 + j
    int c   = (g & 15) << 2;     // channel offset (float4 chunk)

    int j  = pos % CROP;
    int t  = pos / CROP;
    int i  = t % CROP;
    int t2 = t / CROP;
    int n  = t2 & 63;
    int b  = t2 >> 6;

    // load roi (16B aligned: stride 4 floats)
    const float4 roi = *reinterpret_cast<const float4*>(rois + (((b << 6) + n) << 2));
    const float inv_img = 1.0f / 1024.0f;
    float x1 = roi.x * inv_img;
    float y1 = roi.y * inv_img;
    float x2 = roi.z * inv_img;
    float y2 = roi.w * inv_img;

    const float hm1 = (float)(FH - 1);   // 255
    const float wm1 = (float)(FW - 1);   // 255
    const float inv_cm1 = 1.0f / (float)(CROP - 1);  // 1/55

    float ys = y1 * hm1 + (float)i * (y2 - y1) * hm1 * inv_cm1;
    float xs = x1 * wm1 + (float)j * (x2 - x1) * wm1 * inv_cm1;

    bool valid = (ys >= 0.0f) && (ys <= hm1) && (xs >= 0.0f) && (xs <= wm1);

    float y0f = floorf(ys);
    float x0f = floorf(xs);
    float ly = ys - y0f;
    float lx = xs - x0f;

    int y0  = min(max((int)y0f, 0), FH - 1);
    int y1i = min(y0 + 1, FH - 1);
    int x0  = min(max((int)x0f, 0), FW - 1);
    int x1i = min(x0 + 1, FW - 1);

    const float* base = feats + (size_t)b * (FH * FW * FC);
    const float4 v00 = *reinterpret_cast<const float4*>(base + (size_t)(y0  * FW + x0 ) * FC + c);
    const float4 v01 = *reinterpret_cast<const float4*>(base + (size_t)(y0  * FW + x1i) * FC + c);
    const float4 v10 = *reinterpret_cast<const float4*>(base + (size_t)(y1i * FW + x0 ) * FC + c);
    const float4 v11 = *reinterpret_cast<const float4*>(base + (size_t)(y1i * FW + x1i) * FC + c);

    float4 r;
    {
        float top, bot;
        top = v00.x + (v01.x - v00.x) * lx;
        bot = v10.x + (v11.x - v10.x) * lx;
        r.x = top + (bot - top) * ly;
        top = v00.y + (v01.y - v00.y) * lx;
        bot = v10.y + (v11.y - v10.y) * lx;
        r.y = top + (bot - top) * ly;
        top = v00.z + (v01.z - v00.z) * lx;
        bot = v10.z + (v11.z - v10.z) * lx;
        r.z = top + (bot - top) * ly;
        top = v00.w + (v01.w - v00.w) * lx;
        bot = v10.w + (v11.w - v10.w) * lx;
        r.w = top + (bot - top) * ly;
    }
    if (!valid) { r.x = 0.0f; r.y = 0.0f; r.z = 0.0f; r.w = 0.0f; }

    *reinterpret_cast<float4*>(out + (size_t)pos * FC + c) = r;
}

extern "C" void kernel_launch(void* const* d_in, const int* in_sizes, int n_in,
                              void* d_out, int out_size, void* d_ws, size_t ws_size,
                              hipStream_t stream) {
    const float* feats = (const float*)d_in[0];
    const float* rois  = (const float*)d_in[1];
    float* out = (float*)d_out;

    const int total_pos = 4 * 64 * CROP * CROP;      // 802816
    const int total_threads = total_pos * 16;        // 12845056
    const int block = 256;
    const int grid = (total_threads + block - 1) / block;  // 50176

    roialign_kernel<<<grid, block, 0, stream>>>(feats, rois, out, total_threads);
}

// Round 3
// 269.657 us; speedup vs baseline: 1.0434x; 1.0434x over previous
//
#include <hip/hip_runtime.h>

// ROIAlign (tf.image.crop_and_resize, bilinear, extrapolation_value=0)
// features: [B=4, H=256, W=256, C=64] f32
// rois:     [B=4, N=64, 4] f32  (x1,y1,x2,y2) in image coords (/1024 normalized)
// out:      [B=4, N=64, 56, 56, C=64] f32
//
// Layout: 16 lanes per spatial position (4 channels each, float4);
// each thread processes TWO positions sharing j (rows i, i+1) -> shared
// x-coordinate math, 8 independent 16B loads in flight per thread.
// Output stores are non-temporal (native ext_vector_type for the builtin):
// the 205 MB write stream bypasses L2 so feature lines (16 MB/image vs
// 4 MiB/XCD L2) stay resident for re-reads.

#define CROP 56
#define FH 256
#define FW 256
#define FC 64

typedef float f32x4 __attribute__((ext_vector_type(4)));

__device__ __forceinline__ f32x4 lerp2d(f32x4 v00, f32x4 v01, f32x4 v10, f32x4 v11,
                                        float lx, float ly) {
    f32x4 top = v00 + (v01 - v00) * lx;
    f32x4 bot = v10 + (v11 - v10) * lx;
    return top + (bot - top) * ly;
}

__global__ __launch_bounds__(256) void roialign_kernel(
    const float* __restrict__ feats,
    const float* __restrict__ rois,
    float* __restrict__ out)
{
    const int g = blockIdx.x * 256 + threadIdx.x;

    const int c = (g & 15) << 2;          // channel offset (float4 chunk)
    const int p = g >> 4;                 // position-pair index
    const int j  = p % CROP;
    const int t  = p / CROP;
    const int ih = t % (CROP / 2);
    const int rIdx = t / (CROP / 2);      // b*64 + n
    const int i0 = ih * 2;
    const int b  = rIdx >> 6;

    const f32x4 roi = *reinterpret_cast<const f32x4*>(rois + rIdx * 4);
    const float inv_img = 1.0f / 1024.0f;
    const float x1 = roi.x * inv_img;
    const float y1 = roi.y * inv_img;
    const float x2 = roi.z * inv_img;
    const float y2 = roi.w * inv_img;

    const float hm1 = (float)(FH - 1);            // 255
    const float wm1 = (float)(FW - 1);            // 255
    const float inv_cm1 = 1.0f / (float)(CROP - 1);

    // x math shared by both positions
    const float xs = x1 * wm1 + (float)j * (x2 - x1) * wm1 * inv_cm1;
    const bool xvalid = (xs >= 0.0f) && (xs <= wm1);
    const float x0f = floorf(xs);
    const float lx = xs - x0f;
    const int x0  = min(max((int)x0f, 0), FW - 1);
    const int x1i = min(x0 + 1, FW - 1);

    // y math per position (same formulation as the validated round-1 kernel)
    const float ysA = y1 * hm1 + (float)i0 * (y2 - y1) * hm1 * inv_cm1;
    const float ysB = y1 * hm1 + (float)(i0 + 1) * (y2 - y1) * hm1 * inv_cm1;
    const bool validA = xvalid && (ysA >= 0.0f) && (ysA <= hm1);
    const bool validB = xvalid && (ysB >= 0.0f) && (ysB <= hm1);

    const float y0fA = floorf(ysA);
    const float y0fB = floorf(ysB);
    const float lyA = ysA - y0fA;
    const float lyB = ysB - y0fB;
    const int y0A  = min(max((int)y0fA, 0), FH - 1);
    const int y1A  = min(y0A + 1, FH - 1);
    const int y0B  = min(max((int)y0fB, 0), FH - 1);
    const int y1B  = min(y0B + 1, FH - 1);

    const float* base = feats + (size_t)b * (FH * FW * FC) + c;

    // Issue all 8 loads up front for maximum memory-level parallelism.
    const f32x4 a00 = *reinterpret_cast<const f32x4*>(base + (size_t)(y0A * FW + x0 ) * FC);
    const f32x4 a01 = *reinterpret_cast<const f32x4*>(base + (size_t)(y0A * FW + x1i) * FC);
    const f32x4 a10 = *reinterpret_cast<const f32x4*>(base + (size_t)(y1A * FW + x0 ) * FC);
    const f32x4 a11 = *reinterpret_cast<const f32x4*>(base + (size_t)(y1A * FW + x1i) * FC);
    const f32x4 b00 = *reinterpret_cast<const f32x4*>(base + (size_t)(y0B * FW + x0 ) * FC);
    const f32x4 b01 = *reinterpret_cast<const f32x4*>(base + (size_t)(y0B * FW + x1i) * FC);
    const f32x4 b10 = *reinterpret_cast<const f32x4*>(base + (size_t)(y1B * FW + x0 ) * FC);
    const f32x4 b11 = *reinterpret_cast<const f32x4*>(base + (size_t)(y1B * FW + x1i) * FC);

    f32x4 rA = lerp2d(a00, a01, a10, a11, lx, lyA);
    f32x4 rB = lerp2d(b00, b01, b10, b11, lx, lyB);
    if (!validA) { rA = (f32x4)(0.0f); }
    if (!validB) { rB = (f32x4)(0.0f); }

    // out position indices
    const size_t posA = (size_t)rIdx * (CROP * CROP) + (size_t)i0 * CROP + j;
    float* outA = out + posA * FC + c;
    __builtin_nontemporal_store(rA, reinterpret_cast<f32x4*>(outA));
    __builtin_nontemporal_store(rB, reinterpret_cast<f32x4*>(outA + (size_t)CROP * FC));
}

extern "C" void kernel_launch(void* const* d_in, const int* in_sizes, int n_in,
                              void* d_out, int out_size, void* d_ws, size_t ws_size,
                              hipStream_t stream) {
    const float* feats = (const float*)d_in[0];
    const float* rois  = (const float*)d_in[1];
    float* out = (float*)d_out;

    const int total_pairs = 4 * 64 * CROP * (CROP / 2);   // 401408
    const int total_threads = total_pairs * 16;           // 6422528
    const int block = 256;
    const int grid = total_threads / block;               // 25088 (exact)

    roialign_kernel<<<grid, block, 0, stream>>>(feats, rois, out);
}